// Round 1
// baseline (697.983 us; speedup 1.0000x reference)
//
#include <hip/hip_runtime.h>

#define B_ 4096
#define T_ 128
#define DD_ 21
#define H_ 64
#define L_ 32

typedef _Float16 f16;
typedef _Float16 f16x8 __attribute__((ext_vector_type(8)));
typedef float f32x4 __attribute__((ext_vector_type(4)));

#if __has_builtin(__builtin_amdgcn_exp2f)
#define EXP2F(x) __builtin_amdgcn_exp2f(x)
#else
#define EXP2F(x) exp2f(x)
#endif
#if __has_builtin(__builtin_amdgcn_rcpf)
#define RCPF(x) __builtin_amdgcn_rcpf(x)
#else
#define RCPF(x) (1.0f / (x))
#endif

__device__ __forceinline__ float sigmoid_(float x) {
    return RCPF(1.0f + EXP2F(-1.4426950408889634f * x));
}
__device__ __forceinline__ float tanh_(float x) {
    return 1.0f - 2.0f * RCPF(1.0f + EXP2F(2.8853900817779268f * x));
}

#define MFMA16(A, Bf, C) __builtin_amdgcn_mfma_f32_16x16x32_f16((A), (Bf), (C), 0, 0, 0)

// One LSTM layer, fused input projection, optional fused output projection.
// Block: 256 threads = 4 waves, 16 batch rows. Wave w owns gate tiles {w,w+4,w+8,w+12}
// so i/f/g/o for a given (row,hcol) are lane-local. h exchanged via swizzled LDS.
template<int DIN, bool IN_HALF, bool REV_IN, bool WRITE_SEQ, bool WRITE_HT, bool FUSE_OUT, bool LOAD_H0>
__global__ __launch_bounds__(256, 1)
void lstm_k(const float* __restrict__ xf, const f16* __restrict__ xh,
            const float* __restrict__ Wih, const float* __restrict__ Whh,
            const float* __restrict__ bih, const float* __restrict__ bhh,
            const float* __restrict__ h0p,
            f16* __restrict__ seq_out, float* __restrict__ hT_out,
            const float* __restrict__ outW, const float* __restrict__ outb,
            float* __restrict__ rec_out)
{
    __shared__ __align__(16) f16 hbuf[2][16 * 64];
    const int tid  = threadIdx.x;
    const int w    = tid >> 6;
    const int lane = tid & 63;
    const int l15  = lane & 15;
    const int lh   = lane >> 4;
    const int rbase = blockIdx.x * 16;

    // ---- weights into registers (B-frag: col = lane&15, k = (lane>>4)*8 + j) ----
    f16x8 bW[4][2], bX[4][2];
    float biasv[4];
#pragma unroll
    for (int q = 0; q < 4; ++q) {
        const int g = (w + 4 * q) * 16 + l15;   // gate column; q=0:i 1:f 2:g 3:o
#pragma unroll
        for (int kt = 0; kt < 2; ++kt) {
            const float* p = Whh + g * H_ + kt * 32 + lh * 8;
            f16x8 v;
#pragma unroll
            for (int j = 0; j < 8; ++j) v[j] = (f16)p[j];
            bW[q][kt] = v;
        }
        if (DIN == 64) {
#pragma unroll
            for (int kt = 0; kt < 2; ++kt) {
                const float* p = Wih + g * 64 + kt * 32 + lh * 8;
                f16x8 v;
#pragma unroll
                for (int j = 0; j < 8; ++j) v[j] = (f16)p[j];
                bX[q][kt] = v;
            }
        } else {
            f16x8 v;
#pragma unroll
            for (int j = 0; j < 8; ++j) {
                const int k = lh * 8 + j;
                v[j] = (k < DIN) ? (f16)Wih[g * DIN + k] : (f16)0.0f;
            }
            bX[q][0] = v;
            bX[q][1] = v; // unused for DIN<=32
        }
        biasv[q] = bih[g] + bhh[g];
    }

    f16x8 bO[2];
    float obias = 0.0f;
    if (FUSE_OUT) {
        const int d = w * 16 + l15;
#pragma unroll
        for (int kt = 0; kt < 2; ++kt) {
            f16x8 v;
#pragma unroll
            for (int j = 0; j < 8; ++j) {
                const int k = kt * 32 + lh * 8 + j;
                v[j] = (w < 2 && d < DD_) ? (f16)outW[d * H_ + k] : (f16)0.0f;
            }
            bO[kt] = v;
        }
        if (w < 2 && d < DD_) obias = outb[d];
    }

    // ---- init state ----
    f32x4 c4 = {0.f, 0.f, 0.f, 0.f};
    f16x8 hA[2];   // h A-frags: row = lane&15, k = kt*32 + (lane>>4)*8 + j
    if (LOAD_H0) {
#pragma unroll
        for (int kt = 0; kt < 2; ++kt) {
            const float* p = h0p + (size_t)(rbase + l15) * H_ + kt * 32 + lh * 8;
            f16x8 v;
#pragma unroll
            for (int j = 0; j < 8; ++j) v[j] = (f16)p[j];
            hA[kt] = v;
        }
    } else {
#pragma unroll
        for (int j = 0; j < 8; ++j) { hA[0][j] = (f16)0.0f; hA[1][j] = (f16)0.0f; }
    }

    // ---- x fragments for t=0 ----
    f16x8 xA[2];
    if (!IN_HALF) {
        const int trd = REV_IN ? (T_ - 1) : 0;
        const float* px = xf + ((size_t)(rbase + l15) * T_ + trd) * DIN + lh * 8;
        f16x8 v;
#pragma unroll
        for (int j = 0; j < 8; ++j) {
            const int k = lh * 8 + j;
            v[j] = (k < DIN) ? (f16)px[j] : (f16)0.0f;
        }
        xA[0] = v;
#pragma unroll
        for (int j = 0; j < 8; ++j) xA[1][j] = (f16)0.0f;
    } else {
        const f16* px = xh + ((size_t)(rbase + l15) * T_) * H_ + lh * 8;
        xA[0] = *(const f16x8*)(px);
        xA[1] = *(const f16x8*)(px + 32);
    }

#pragma unroll 2
    for (int t = 0; t < T_; ++t) {
        // ---- prefetch x for t+1 (latency hidden under MFMA+activations) ----
        float xr[8];
        f16x8 xn0, xn1;
        const int tn = (t + 1 < T_) ? (t + 1) : t;
        if (!IN_HALF) {
            const int trd = REV_IN ? (T_ - 1 - tn) : tn;
            const float* px = xf + ((size_t)(rbase + l15) * T_ + trd) * DIN + lh * 8;
#pragma unroll
            for (int j = 0; j < 8; ++j) {
                const int k = lh * 8 + j;
                xr[j] = (k < DIN) ? px[j] : 0.0f;
            }
        } else {
            const f16* px = xh + ((size_t)(rbase + l15) * T_ + tn) * H_ + lh * 8;
            xn0 = *(const f16x8*)(px);
            xn1 = *(const f16x8*)(px + 32);
        }

        // ---- gates = bias + x@Wih^T + h@Whh^T ----
        f32x4 acc[4];
#pragma unroll
        for (int q = 0; q < 4; ++q) {
            f32x4 a = {biasv[q], biasv[q], biasv[q], biasv[q]};
            a = MFMA16(xA[0], bX[q][0], a);
            if (DIN == 64) a = MFMA16(xA[1], bX[q][1], a);
            a = MFMA16(hA[0], bW[q][0], a);
            a = MFMA16(hA[1], bW[q][1], a);
            acc[q] = a;
        }

        // ---- lane-local activations / state update (D-layout: row=lh*4+r, col=l15) ----
        f16 hh[4];
#pragma unroll
        for (int r = 0; r < 4; ++r) {
            const float iv = sigmoid_(acc[0][r]);
            const float fv = sigmoid_(acc[1][r]);
            const float gv = tanh_(acc[2][r]);
            const float ov = sigmoid_(acc[3][r]);
            const float cn = fv * c4[r] + iv * gv;
            c4[r] = cn;
            const float hv = ov * tanh_(cn);
            hh[r] = (f16)hv;
            const int row = lh * 4 + r;
            if (WRITE_SEQ)
                seq_out[((size_t)(rbase + row) * T_ + t) * H_ + w * 16 + l15] = hh[r];
            if (WRITE_HT && t == T_ - 1)
                hT_out[(size_t)(rbase + row) * H_ + w * 16 + l15] = hv;
        }

        // ---- exchange h via swizzled LDS (write D-layout, read A-layout) ----
        {
            char* base = (char*)(&hbuf[t & 1][0]);
            const int colb = (w * 16 + l15) * 2;
#pragma unroll
            for (int r = 0; r < 4; ++r) {
                const int row = lh * 4 + r;
                *(f16*)(base + row * 128 + (colb ^ ((row & 7) << 4))) = hh[r];
            }
        }
        __syncthreads();
        {
            const char* base = (const char*)(&hbuf[t & 1][0]);
            const int sw = (l15 & 7) << 4;
            hA[0] = *(const f16x8*)(base + l15 * 128 + ((lh * 16) ^ sw));
            hA[1] = *(const f16x8*)(base + l15 * 128 + ((64 + lh * 16) ^ sw));
        }

        // ---- fused output projection: rec[:, T-1-t, :] = h_t @ outW^T + outb ----
        if (FUSE_OUT && w < 2) {
            f32x4 ao = {obias, obias, obias, obias};
            ao = MFMA16(hA[0], bO[0], ao);
            ao = MFMA16(hA[1], bO[1], ao);
            const int d = w * 16 + l15;
            if (d < DD_) {
#pragma unroll
                for (int r = 0; r < 4; ++r)
                    rec_out[((size_t)(rbase + lh * 4 + r) * T_ + (T_ - 1 - t)) * DD_ + d] = ao[r];
            }
        }

        // ---- commit prefetched x ----
        if (!IN_HALF) {
            f16x8 v;
#pragma unroll
            for (int j = 0; j < 8; ++j) v[j] = (f16)xr[j];
            xA[0] = v;
        } else {
            xA[0] = xn0;
            xA[1] = xn1;
        }
    }
}

// latent = hT2 @ tlW^T + tlb ; h0 = latent @ flW^T + flb   (tiny, fp32 VALU)
__global__ __launch_bounds__(256)
void latent_k(const float* __restrict__ hT, const float* __restrict__ tlW,
              const float* __restrict__ tlb, const float* __restrict__ flW,
              const float* __restrict__ flb, float* __restrict__ lat_out,
              float* __restrict__ h0_out)
{
    __shared__ float lat[64][L_];
    const int tid = threadIdx.x;
    const int r = tid >> 2;
    const int rb = blockIdx.x * 64;

    float hr[H_];
    const float* hrow = hT + (size_t)(rb + r) * H_;
#pragma unroll
    for (int k = 0; k < H_; ++k) hr[k] = hrow[k];

    const int c8 = (tid & 3) * 8;
#pragma unroll
    for (int jj = 0; jj < 8; ++jj) {
        const int l = c8 + jj;
        float s = tlb[l];
        const float* wrow = tlW + l * H_;
#pragma unroll
        for (int k = 0; k < H_; ++k) s += hr[k] * wrow[k];
        lat[r][l] = s;
        lat_out[(size_t)(rb + r) * L_ + l] = s;
    }
    __syncthreads();

    float lr[L_];
#pragma unroll
    for (int k = 0; k < L_; ++k) lr[k] = lat[r][k];
    const int hc16 = (tid & 3) * 16;
#pragma unroll
    for (int jj = 0; jj < 16; ++jj) {
        const int hc = hc16 + jj;
        float s = flb[hc];
        const float* wrow = flW + hc * L_;
#pragma unroll
        for (int k = 0; k < L_; ++k) s += lr[k] * wrow[k];
        h0_out[(size_t)(rb + r) * H_ + hc] = s;
    }
}

extern "C" void kernel_launch(void* const* d_in, const int* in_sizes, int n_in,
                              void* d_out, int out_size, void* d_ws, size_t ws_size,
                              hipStream_t stream)
{
    const float* x     = (const float*)d_in[0];
    const float* eWih0 = (const float*)d_in[1];
    const float* eWhh0 = (const float*)d_in[2];
    const float* ebih0 = (const float*)d_in[3];
    const float* ebhh0 = (const float*)d_in[4];
    const float* eWih1 = (const float*)d_in[5];
    const float* eWhh1 = (const float*)d_in[6];
    const float* ebih1 = (const float*)d_in[7];
    const float* ebhh1 = (const float*)d_in[8];
    const float* dWih0 = (const float*)d_in[9];
    const float* dWhh0 = (const float*)d_in[10];
    const float* dbih0 = (const float*)d_in[11];
    const float* dbhh0 = (const float*)d_in[12];
    const float* dWih1 = (const float*)d_in[13];
    const float* dWhh1 = (const float*)d_in[14];
    const float* dbih1 = (const float*)d_in[15];
    const float* dbhh1 = (const float*)d_in[16];
    const float* tlW   = (const float*)d_in[17];
    const float* tlb   = (const float*)d_in[18];
    const float* flW   = (const float*)d_in[19];
    const float* flb   = (const float*)d_in[20];
    const float* outW  = (const float*)d_in[21];
    const float* outb  = (const float*)d_in[22];

    float* rec = (float*)d_out;                       // [B,T,21] fp32
    float* lat = rec + (size_t)B_ * T_ * DD_;         // [B,32]  fp32

    char* ws = (char*)d_ws;
    f16*   seqbuf = (f16*)ws;                                                  // [B,T,64] f16 (h1, then d1)
    float* hT2    = (float*)(ws + (size_t)B_ * T_ * H_ * 2);                   // [B,64]
    float* h0     = (float*)(ws + (size_t)B_ * T_ * H_ * 2 + (size_t)B_ * H_ * 4); // [B,64]

    dim3 grid(B_ / 16), blk(256);
    // encoder layer 0: x (fp32) -> h1 seq (f16)
    lstm_k<21, false, false, true, false, false, false><<<grid, blk, 0, stream>>>(
        x, nullptr, eWih0, eWhh0, ebih0, ebhh0, nullptr, seqbuf, nullptr, nullptr, nullptr, nullptr);
    // encoder layer 1: h1 -> hT2 only
    lstm_k<64, true, false, false, true, false, false><<<grid, blk, 0, stream>>>(
        nullptr, seqbuf, eWih1, eWhh1, ebih1, ebhh1, nullptr, nullptr, hT2, nullptr, nullptr, nullptr);
    // latent + decoder initial h
    latent_k<<<dim3(B_ / 64), blk, 0, stream>>>(hT2, tlW, tlb, flW, flb, lat, h0);
    // decoder layer 0: reversed x, h0 -> d1 seq (f16, overwrites h1)
    lstm_k<21, false, true, true, false, false, true><<<grid, blk, 0, stream>>>(
        x, nullptr, dWih0, dWhh0, dbih0, dbhh0, h0, seqbuf, nullptr, nullptr, nullptr, nullptr);
    // decoder layer 1: d1, h0 -> rec (fused out-proj, time-reversed store)
    lstm_k<64, true, false, false, false, true, true><<<grid, blk, 0, stream>>>(
        nullptr, seqbuf, dWih1, dWhh1, dbih1, dbhh1, h0, nullptr, nullptr, outW, outb, rec);
}

// Round 2
// 676.767 us; speedup vs baseline: 1.0313x; 1.0313x over previous
//
#include <hip/hip_runtime.h>

#define B_ 4096
#define T_ 128
#define DD_ 21
#define H_ 64
#define L_ 32

typedef _Float16 f16;
typedef _Float16 f16x8 __attribute__((ext_vector_type(8)));
typedef float f32x4 __attribute__((ext_vector_type(4)));

#if __has_builtin(__builtin_amdgcn_exp2f)
#define EXP2F(x) __builtin_amdgcn_exp2f(x)
#else
#define EXP2F(x) exp2f(x)
#endif
#if __has_builtin(__builtin_amdgcn_rcpf)
#define RCPF(x) __builtin_amdgcn_rcpf(x)
#else
#define RCPF(x) (1.0f / (x))
#endif

__device__ __forceinline__ float sigmoid_(float x) {
    return RCPF(1.0f + EXP2F(-1.4426950408889634f * x));
}
__device__ __forceinline__ float tanh_(float x) {
    return 1.0f - 2.0f * RCPF(1.0f + EXP2F(2.8853900817779268f * x));
}

#define MFMA16(A, Bf, C) __builtin_amdgcn_mfma_f32_16x16x32_f16((A), (Bf), (C), 0, 0, 0)

// One LSTM layer, fused input projection, optional fused output projection.
// Block: 256 threads = 4 waves, 16 batch rows (1 block/CU; B/16 = 256 blocks).
// Wave w owns gate tiles {w,w+4,w+8,w+12} so i/f/g/o for a (row,hcol) are lane-local.
// Weight fragments live in LDS in frag order: [wave][q*2+kt][lane] 16B/lane ->
// ds_read_b128, linear, conflict-free, each lane reads what it staged.
// (Round-1 kernel kept weights in "registers": VGPR_Count=76 < live set => spill
//  => 3770 cyc/step. LDS staging removes the invariant register pressure.)
template<int DIN, bool IN_HALF, bool REV_IN, bool WRITE_SEQ, bool WRITE_HT, bool FUSE_OUT, bool LOAD_H0>
__global__ __launch_bounds__(256, 1)
void lstm_k(const float* __restrict__ xf, const f16* __restrict__ xh,
            const float* __restrict__ Wih, const float* __restrict__ Whh,
            const float* __restrict__ bih, const float* __restrict__ bhh,
            const float* __restrict__ h0p,
            f16* __restrict__ seq_out, float* __restrict__ hT_out,
            const float* __restrict__ outW, const float* __restrict__ outb,
            float* __restrict__ rec_out)
{
    constexpr int NX = (DIN == 64) ? 8 : 4;   // Wih frag slots per wave
    __shared__ __align__(16) f16 hbuf[2][16 * 64];
    __shared__ f16x8 wlds[4][8][64];          // Whh frags, 32 KB
    __shared__ f16x8 xlds[4][NX][64];         // Wih frags, 16/32 KB

    const int tid  = threadIdx.x;
    const int w    = tid >> 6;
    const int lane = tid & 63;
    const int l15  = lane & 15;
    const int lh   = lane >> 4;
    const int rbase = blockIdx.x * 16;

    // ---- stage weight fragments into LDS (each thread stages what it will read) ----
    float biasv[4];
#pragma unroll
    for (int q = 0; q < 4; ++q) {
        const int g = (w + 4 * q) * 16 + l15;   // gate column; q=0:i 1:f 2:g 3:o
#pragma unroll
        for (int kt = 0; kt < 2; ++kt) {
            const float* p = Whh + g * H_ + kt * 32 + lh * 8;
            f16x8 v;
#pragma unroll
            for (int j = 0; j < 8; ++j) v[j] = (f16)p[j];
            wlds[w][q * 2 + kt][lane] = v;
        }
        if (DIN == 64) {
#pragma unroll
            for (int kt = 0; kt < 2; ++kt) {
                const float* p = Wih + g * 64 + kt * 32 + lh * 8;
                f16x8 v;
#pragma unroll
                for (int j = 0; j < 8; ++j) v[j] = (f16)p[j];
                xlds[w][q * 2 + kt][lane] = v;
            }
        } else {
            const float* p = Wih + g * DIN;
            f16x8 v;
#pragma unroll
            for (int j = 0; j < 8; ++j) {
                const int k = lh * 8 + j;
                v[j] = (k < DIN) ? (f16)p[k] : (f16)0.0f;
            }
            xlds[w][q][lane] = v;
        }
        biasv[q] = bih[g] + bhh[g];
    }

    f16x8 bO[2];
    float obias = 0.0f;
    if (FUSE_OUT) {
        const int d = w * 16 + l15;
#pragma unroll
        for (int kt = 0; kt < 2; ++kt) {
            f16x8 v;
#pragma unroll
            for (int j = 0; j < 8; ++j) {
                const int k = kt * 32 + lh * 8 + j;
                v[j] = (w < 2 && d < DD_) ? (f16)outW[d * H_ + k] : (f16)0.0f;
            }
            bO[kt] = v;
        }
        if (w < 2 && d < DD_) obias = outb[d];
    }

    // ---- init state ----
    f32x4 c4 = {0.f, 0.f, 0.f, 0.f};
    f16x8 hA[2];   // h A-frags: row = lane&15, k = kt*32 + (lane>>4)*8 + j
    if (LOAD_H0) {
#pragma unroll
        for (int kt = 0; kt < 2; ++kt) {
            const float* p = h0p + (size_t)(rbase + l15) * H_ + kt * 32 + lh * 8;
            f16x8 v;
#pragma unroll
            for (int j = 0; j < 8; ++j) v[j] = (f16)p[j];
            hA[kt] = v;
        }
    } else {
#pragma unroll
        for (int j = 0; j < 8; ++j) { hA[0][j] = (f16)0.0f; hA[1][j] = (f16)0.0f; }
    }

    __syncthreads();   // weights staged

    // ---- x prefetch ring, distance 2 ----
    // xA holds frag for current t; pf[(t+1)&1] holds raw data for t+1;
    // at iter t we issue the load for t+2 into pf[t&1].
    f16x8 xA[2];
    float pfF[2][8];       // raw fp32 ring (DIN=21 path)
    f16x8 pfH[2][2];       // f16 ring (IN_HALF path)

    auto xaddr_f = [&](int t) -> const float* {
        const int trd = REV_IN ? (T_ - 1 - t) : t;
        return xf + ((size_t)(rbase + l15) * T_ + trd) * DIN + lh * 8;
    };
    auto xaddr_h = [&](int t) -> const f16* {
        return xh + ((size_t)(rbase + l15) * T_ + t) * H_ + lh * 8;
    };

    if (!IN_HALF) {
        const float* p0 = xaddr_f(0);
        f16x8 v;
#pragma unroll
        for (int j = 0; j < 8; ++j) {
            const int k = lh * 8 + j;
            v[j] = (k < DIN) ? (f16)p0[j] : (f16)0.0f;
        }
        xA[0] = v;
#pragma unroll
        for (int j = 0; j < 8; ++j) xA[1][j] = (f16)0.0f;
        const float* p1 = xaddr_f(1 < T_ ? 1 : 0);
#pragma unroll
        for (int j = 0; j < 8; ++j) {
            const int k = lh * 8 + j;
            pfF[1][j] = (k < DIN) ? p1[j] : 0.0f;
        }
    } else {
        const f16* p0 = xaddr_h(0);
        xA[0] = *(const f16x8*)(p0);
        xA[1] = *(const f16x8*)(p0 + 32);
        const f16* p1 = xaddr_h(1 < T_ ? 1 : 0);
        pfH[1][0] = *(const f16x8*)(p1);
        pfH[1][1] = *(const f16x8*)(p1 + 32);
    }

#pragma unroll 2
    for (int t = 0; t < T_; ++t) {
        // ---- issue load for t+2 into pf[t&1] (covered by ~2 steps of compute) ----
        const int tf = (t + 2 < T_) ? (t + 2) : (T_ - 1);
        if (!IN_HALF) {
            const float* px = xaddr_f(tf);
#pragma unroll
            for (int j = 0; j < 8; ++j) {
                const int k = lh * 8 + j;
                pfF[t & 1][j] = (k < DIN) ? px[j] : 0.0f;
            }
        } else {
            const f16* px = xaddr_h(tf);
            pfH[t & 1][0] = *(const f16x8*)(px);
            pfH[t & 1][1] = *(const f16x8*)(px + 32);
        }

        // ---- gates = bias + x@Wih^T + h@Whh^T (weight frags via ds_read_b128) ----
        f32x4 acc[4];
#pragma unroll
        for (int q = 0; q < 4; ++q) {
            f32x4 a = {biasv[q], biasv[q], biasv[q], biasv[q]};
            a = MFMA16(xA[0], xlds[w][DIN == 64 ? q * 2 : q][lane], a);
            if (DIN == 64) a = MFMA16(xA[1], xlds[w][q * 2 + 1][lane], a);
            a = MFMA16(hA[0], wlds[w][q * 2 + 0][lane], a);
            a = MFMA16(hA[1], wlds[w][q * 2 + 1][lane], a);
            acc[q] = a;
        }

        // ---- lane-local activations / state update (D-layout: row=lh*4+r, col=l15) ----
        f16 hh[4];
#pragma unroll
        for (int r = 0; r < 4; ++r) {
            const float iv = sigmoid_(acc[0][r]);
            const float fv = sigmoid_(acc[1][r]);
            const float gv = tanh_(acc[2][r]);
            const float ov = sigmoid_(acc[3][r]);
            const float cn = fv * c4[r] + iv * gv;
            c4[r] = cn;
            const float hv = ov * tanh_(cn);
            hh[r] = (f16)hv;
            const int row = lh * 4 + r;
            if (WRITE_SEQ)
                seq_out[((size_t)(rbase + row) * T_ + t) * H_ + w * 16 + l15] = hh[r];
            if (WRITE_HT && t == T_ - 1)
                hT_out[(size_t)(rbase + row) * H_ + w * 16 + l15] = hv;
        }

        // ---- exchange h via swizzled LDS (write D-layout, read A-layout) ----
        {
            char* base = (char*)(&hbuf[t & 1][0]);
            const int colb = (w * 16 + l15) * 2;
#pragma unroll
            for (int r = 0; r < 4; ++r) {
                const int row = lh * 4 + r;
                *(f16*)(base + row * 128 + (colb ^ ((row & 7) << 4))) = hh[r];
            }
        }
        __syncthreads();
        {
            const char* base = (const char*)(&hbuf[t & 1][0]);
            const int sw = (l15 & 7) << 4;
            hA[0] = *(const f16x8*)(base + l15 * 128 + ((lh * 16) ^ sw));
            hA[1] = *(const f16x8*)(base + l15 * 128 + ((64 + lh * 16) ^ sw));
        }

        // ---- fused output projection: rec[:, T-1-t, :] = h_t @ outW^T + outb ----
        if (FUSE_OUT && w < 2) {
            f32x4 ao = {obias, obias, obias, obias};
            ao = MFMA16(hA[0], bO[0], ao);
            ao = MFMA16(hA[1], bO[1], ao);
            const int d = w * 16 + l15;
            if (d < DD_) {
#pragma unroll
                for (int r = 0; r < 4; ++r)
                    rec_out[((size_t)(rbase + lh * 4 + r) * T_ + (T_ - 1 - t)) * DD_ + d] = ao[r];
            }
        }

        // ---- commit prefetched x for t+1 ----
        if (!IN_HALF) {
            f16x8 v;
#pragma unroll
            for (int j = 0; j < 8; ++j) v[j] = (f16)pfF[(t + 1) & 1][j];
            xA[0] = v;
        } else {
            xA[0] = pfH[(t + 1) & 1][0];
            xA[1] = pfH[(t + 1) & 1][1];
        }
    }
}

// latent = hT2 @ tlW^T + tlb ; h0 = latent @ flW^T + flb   (tiny, fp32 VALU)
__global__ __launch_bounds__(256)
void latent_k(const float* __restrict__ hT, const float* __restrict__ tlW,
              const float* __restrict__ tlb, const float* __restrict__ flW,
              const float* __restrict__ flb, float* __restrict__ lat_out,
              float* __restrict__ h0_out)
{
    __shared__ float lat[64][L_];
    const int tid = threadIdx.x;
    const int r = tid >> 2;
    const int rb = blockIdx.x * 64;

    float hr[H_];
    const float* hrow = hT + (size_t)(rb + r) * H_;
#pragma unroll
    for (int k = 0; k < H_; ++k) hr[k] = hrow[k];

    const int c8 = (tid & 3) * 8;
#pragma unroll
    for (int jj = 0; jj < 8; ++jj) {
        const int l = c8 + jj;
        float s = tlb[l];
        const float* wrow = tlW + l * H_;
#pragma unroll
        for (int k = 0; k < H_; ++k) s += hr[k] * wrow[k];
        lat[r][l] = s;
        lat_out[(size_t)(rb + r) * L_ + l] = s;
    }
    __syncthreads();

    float lr[L_];
#pragma unroll
    for (int k = 0; k < L_; ++k) lr[k] = lat[r][k];
    const int hc16 = (tid & 3) * 16;
#pragma unroll
    for (int jj = 0; jj < 16; ++jj) {
        const int hc = hc16 + jj;
        float s = flb[hc];
        const float* wrow = flW + hc * L_;
#pragma unroll
        for (int k = 0; k < L_; ++k) s += lr[k] * wrow[k];
        h0_out[(size_t)(rb + r) * H_ + hc] = s;
    }
}

extern "C" void kernel_launch(void* const* d_in, const int* in_sizes, int n_in,
                              void* d_out, int out_size, void* d_ws, size_t ws_size,
                              hipStream_t stream)
{
    const float* x     = (const float*)d_in[0];
    const float* eWih0 = (const float*)d_in[1];
    const float* eWhh0 = (const float*)d_in[2];
    const float* ebih0 = (const float*)d_in[3];
    const float* ebhh0 = (const float*)d_in[4];
    const float* eWih1 = (const float*)d_in[5];
    const float* eWhh1 = (const float*)d_in[6];
    const float* ebih1 = (const float*)d_in[7];
    const float* ebhh1 = (const float*)d_in[8];
    const float* dWih0 = (const float*)d_in[9];
    const float* dWhh0 = (const float*)d_in[10];
    const float* dbih0 = (const float*)d_in[11];
    const float* dbhh0 = (const float*)d_in[12];
    const float* dWih1 = (const float*)d_in[13];
    const float* dWhh1 = (const float*)d_in[14];
    const float* dbih1 = (const float*)d_in[15];
    const float* dbhh1 = (const float*)d_in[16];
    const float* tlW   = (const float*)d_in[17];
    const float* tlb   = (const float*)d_in[18];
    const float* flW   = (const float*)d_in[19];
    const float* flb   = (const float*)d_in[20];
    const float* outW  = (const float*)d_in[21];
    const float* outb  = (const float*)d_in[22];

    float* rec = (float*)d_out;                       // [B,T,21] fp32
    float* lat = rec + (size_t)B_ * T_ * DD_;         // [B,32]  fp32

    char* ws = (char*)d_ws;
    f16*   seqbuf = (f16*)ws;                                                  // [B,T,64] f16 (h1, then d1)
    float* hT2    = (float*)(ws + (size_t)B_ * T_ * H_ * 2);                   // [B,64]
    float* h0     = (float*)(ws + (size_t)B_ * T_ * H_ * 2 + (size_t)B_ * H_ * 4); // [B,64]

    dim3 grid(B_ / 16), blk(256);
    // encoder layer 0: x (fp32) -> h1 seq (f16)
    lstm_k<21, false, false, true, false, false, false><<<grid, blk, 0, stream>>>(
        x, nullptr, eWih0, eWhh0, ebih0, ebhh0, nullptr, seqbuf, nullptr, nullptr, nullptr, nullptr);
    // encoder layer 1: h1 -> hT2 only
    lstm_k<64, true, false, false, true, false, false><<<grid, blk, 0, stream>>>(
        nullptr, seqbuf, eWih1, eWhh1, ebih1, ebhh1, nullptr, nullptr, hT2, nullptr, nullptr, nullptr);
    // latent + decoder initial h
    latent_k<<<dim3(B_ / 64), blk, 0, stream>>>(hT2, tlW, tlb, flW, flb, lat, h0);
    // decoder layer 0: reversed x, h0 -> d1 seq (f16, overwrites h1)
    lstm_k<21, false, true, true, false, false, true><<<grid, blk, 0, stream>>>(
        x, nullptr, dWih0, dWhh0, dbih0, dbhh0, h0, seqbuf, nullptr, nullptr, nullptr, nullptr);
    // decoder layer 1: d1, h0 -> rec (fused out-proj, time-reversed store)
    lstm_k<64, true, false, false, false, true, true><<<grid, blk, 0, stream>>>(
        nullptr, seqbuf, dWih1, dWhh1, dbih1, dbhh1, h0, nullptr, nullptr, outW, outb, rec);
}

// Round 3
// 416.679 us; speedup vs baseline: 1.6751x; 1.6242x over previous
//
#include <hip/hip_runtime.h>

#define B_ 4096
#define T_ 128
#define DD_ 21
#define H_ 64
#define L_ 32
#define DP_ 32   // layer-0 input dim padded to 32 (f16)

typedef _Float16 f16;
typedef _Float16 f16x8 __attribute__((ext_vector_type(8)));
typedef _Float16 f16x4 __attribute__((ext_vector_type(4)));
typedef float f32x4 __attribute__((ext_vector_type(4)));

#if __has_builtin(__builtin_amdgcn_exp2f)
#define EXP2F(x) __builtin_amdgcn_exp2f(x)
#else
#define EXP2F(x) exp2f(x)
#endif
#if __has_builtin(__builtin_amdgcn_rcpf)
#define RCPF(x) __builtin_amdgcn_rcpf(x)
#else
#define RCPF(x) (1.0f / (x))
#endif

__device__ __forceinline__ float sigmoid_(float x) {
    return RCPF(1.0f + EXP2F(-1.4426950408889634f * x));
}
__device__ __forceinline__ float tanh_(float x) {
    return 1.0f - 2.0f * RCPF(1.0f + EXP2F(2.8853900817779268f * x));
}

#define MFMA16(A, Bf, C) __builtin_amdgcn_mfma_f32_16x16x32_f16((A), (Bf), (C), 0, 0, 0)

// ---- h ring helpers: [2 slots][16 rows][64 cols] f16, XOR-swizzled rows ----
// write side: D-frag (row=lh*4+r, col=w*16+l15); read side: A-frag (row=l15, k)
__device__ __forceinline__ void ring_read(const f16* ring, int slot, int l15, int lh,
                                          f16x8& a0, f16x8& a1) {
    const char* base = (const char*)(ring + slot * 1024);
    const int sw = (l15 & 7) << 4;
    a0 = *(const f16x8*)(base + l15 * 128 + ((lh * 16) ^ sw));
    a1 = *(const f16x8*)(base + l15 * 128 + ((64 + lh * 16) ^ sw));
}
__device__ __forceinline__ void ring_write(f16* ring, int slot, int w, int l15, int lh,
                                           const f16* hh) {
    char* base = (char*)(ring + slot * 1024);
    const int colb = (w * 16 + l15) * 2;
#pragma unroll
    for (int r = 0; r < 4; ++r) {
        const int row = lh * 4 + r;
        *(f16*)(base + row * 128 + (colb ^ ((row & 7) << 4))) = hh[r];
    }
}

// x pad/cast: x f32 [B,T,21] -> xpad f16 [B,T,32] (zero-padded)
__global__ __launch_bounds__(256)
void padx_k(const float* __restrict__ x, f16* __restrict__ xpad)
{
    const int idx = blockIdx.x * blockDim.x + threadIdx.x;   // B*T*8 groups of 4
    const size_t bt = (size_t)(idx >> 3);
    const int k0 = (idx & 7) * 4;
    const float* src = x + bt * DD_;
    f16x4 v;
#pragma unroll
    for (int j = 0; j < 4; ++j) {
        const int k = k0 + j;
        v[j] = (k < DD_) ? (f16)src[k] : (f16)0.0f;
    }
    *(f16x4*)(xpad + bt * DP_ + k0) = v;
}

// Fused layer pair with 1-step pipeline skew.
// Block: 512 threads = 8 waves. Waves 0-3: layer0 (t=s), waves 4-7: layer1 (t=s-1).
// h1 flows layer0->layer1 through ring0; ring1 is layer1's own recurrence.
// IS_DEC: layer0 reads x reversed, both layers start from h0p, layer1 output is
// projected (outW/outb) and stored time-reversed into rec (at t=s-2, reusing the
// recurrent hA ring read). !IS_DEC: layer1 stores only h_T.
template<bool IS_DEC>
__global__ __launch_bounds__(512, 2)
void lstm_pair_k(const f16* __restrict__ xpad,
                 const float* __restrict__ Wih0, const float* __restrict__ Whh0,
                 const float* __restrict__ bih0, const float* __restrict__ bhh0,
                 const float* __restrict__ Wih1, const float* __restrict__ Whh1,
                 const float* __restrict__ bih1, const float* __restrict__ bhh1,
                 const float* __restrict__ h0p,
                 float* __restrict__ hT_out,
                 const float* __restrict__ outW, const float* __restrict__ outb,
                 float* __restrict__ rec_out)
{
    __shared__ f16x8 wlds0[4][8][64];   // layer0 Whh frags (32 KB)
    __shared__ f16x8 xlds0[4][4][64];   // layer0 Wih frags, K=32 (16 KB)
    __shared__ f16x8 wlds1[4][8][64];   // layer1 Whh frags (32 KB)
    __shared__ f16x8 xlds1[4][8][64];   // layer1 Wih frags (32 KB)
    __shared__ __align__(16) f16 ring0[2 * 1024];   // h1 ring (4 KB)
    __shared__ __align__(16) f16 ring1[2 * 1024];   // h2 ring (4 KB)

    const int tid  = threadIdx.x;
    const int wv   = tid >> 6;
    const int grp  = wv >> 2;         // 0: layer0, 1: layer1
    const int w    = wv & 3;
    const int lane = tid & 63;
    const int l15  = lane & 15;
    const int lh   = lane >> 4;
    const int rbase = blockIdx.x * 16;

    // ---- stage weight fragments (each thread stages what it will read back) ----
    const float* Wih = grp ? Wih1 : Wih0;
    const float* Whh = grp ? Whh1 : Whh0;
    const float* bih = grp ? bih1 : bih0;
    const float* bhh = grp ? bhh1 : bhh0;

    f32x4 bias4[4];
#pragma unroll
    for (int q = 0; q < 4; ++q) {
        const int g = (w + 4 * q) * 16 + l15;   // gate row in W; q=0:i 1:f 2:g 3:o
#pragma unroll
        for (int kt = 0; kt < 2; ++kt) {
            const float* p = Whh + g * H_ + kt * 32 + lh * 8;
            f16x8 v;
#pragma unroll
            for (int j = 0; j < 8; ++j) v[j] = (f16)p[j];
            if (grp) wlds1[w][q * 2 + kt][lane] = v;
            else     wlds0[w][q * 2 + kt][lane] = v;
        }
        if (grp) {
#pragma unroll
            for (int kt = 0; kt < 2; ++kt) {
                const float* p = Wih + g * H_ + kt * 32 + lh * 8;
                f16x8 v;
#pragma unroll
                for (int j = 0; j < 8; ++j) v[j] = (f16)p[j];
                xlds1[w][q * 2 + kt][lane] = v;
            }
        } else {
            const float* p = Wih + g * DD_;     // real row length 21
            f16x8 v;
#pragma unroll
            for (int j = 0; j < 8; ++j) {
                const int k = lh * 8 + j;
                v[j] = (k < DD_) ? (f16)p[k] : (f16)0.0f;
            }
            xlds0[w][q][lane] = v;
        }
        const float bv = bih[g] + bhh[g];
        bias4[q] = (f32x4){bv, bv, bv, bv};
    }

    // out-projection frags (dec layer1, waves 0-1 of grp1 only)
    f16x8 bO[2];
    float obias = 0.0f;
    if (IS_DEC && grp == 1) {
        const int d = w * 16 + l15;
        const bool valid = (w < 2) && (d < DD_);
#pragma unroll
        for (int kt = 0; kt < 2; ++kt) {
            f16x8 v;
#pragma unroll
            for (int j = 0; j < 8; ++j)
                v[j] = valid ? (f16)outW[d * H_ + kt * 32 + lh * 8 + j] : (f16)0.0f;
            bO[kt] = v;
        }
        if (valid) obias = outb[d];
    }

    // ---- init ring slot 1 with h(-1): h0p (dec) or zeros (enc) ----
    {
        f16* ring = (tid < 256) ? ring0 : ring1;
        const int i = tid & 255;
        const int row = i >> 4;
        const int cq = i & 15;
        f16x4 v;
#pragma unroll
        for (int j = 0; j < 4; ++j)
            v[j] = IS_DEC ? (f16)h0p[(size_t)(rbase + row) * H_ + cq * 4 + j] : (f16)0.0f;
        char* base = (char*)(ring + 1024);
        *(f16x4*)(base + row * 128 + ((cq * 8) ^ ((row & 7) << 4))) = v;
    }

    f32x4 c4 = {0.f, 0.f, 0.f, 0.f};

    // ---- layer0 x prefetch ring (distance 2) ----
    auto xaddr = [&](int t) -> const f16* {
        const int trd = IS_DEC ? (T_ - 1 - t) : t;
        return xpad + ((size_t)(rbase + l15) * T_ + trd) * DP_ + lh * 8;
    };
    f16x8 xA, pf[2];
    if (grp == 0) {
        xA = *(const f16x8*)xaddr(0);
        pf[1] = *(const f16x8*)xaddr(1);
    }

    __syncthreads();   // weights + ring init visible

    // ---- pipelined main loop; 130 block-steps (even => clean unroll-2) ----
#pragma unroll 2
    for (int s = 0; s < 130; ++s) {
        if (grp == 0) {
            if (s < T_) {
                // prefetch x(s+2)
                const int tf = (s + 2 < T_) ? s + 2 : T_ - 1;
                pf[s & 1] = *(const f16x8*)xaddr(tf);
                // h1(s-1) from ring0 slot (s-1)&1 == (s+1)&1
                f16x8 hA0, hA1;
                ring_read(ring0, (s + 1) & 1, l15, lh, hA0, hA1);
                f32x4 acc[4];
#pragma unroll
                for (int q = 0; q < 4; ++q) {
                    f32x4 a = MFMA16(xA, xlds0[w][q][lane], bias4[q]);
                    a = MFMA16(hA0, wlds0[w][q * 2 + 0][lane], a);
                    a = MFMA16(hA1, wlds0[w][q * 2 + 1][lane], a);
                    acc[q] = a;
                }
                f16 hh[4];
#pragma unroll
                for (int r = 0; r < 4; ++r) {
                    const float iv = sigmoid_(acc[0][r]);
                    const float fv = sigmoid_(acc[1][r]);
                    const float gv = tanh_(acc[2][r]);
                    const float ov = sigmoid_(acc[3][r]);
                    const float cn = fv * c4[r] + iv * gv;
                    c4[r] = cn;
                    hh[r] = (f16)(ov * tanh_(cn));
                }
                ring_write(ring0, s & 1, w, l15, lh, hh);
                xA = pf[(s + 1) & 1];
            }
        } else {
            if (s >= 1) {
                // own recurrence h2(s-2) from ring1 slot (s-2)&1 == s&1
                f16x8 hA0, hA1;
                ring_read(ring1, s & 1, l15, lh, hA0, hA1);

                // deferred output projection of h2(s-2) (dec only)
                if (IS_DEC && s >= 2) {
                    if (w < 2) {
                        f32x4 ao = {obias, obias, obias, obias};
                        ao = MFMA16(hA0, bO[0], ao);
                        ao = MFMA16(hA1, bO[1], ao);
                        const int d = w * 16 + l15;
                        if (d < DD_) {
                            const int t = s - 2;
#pragma unroll
                            for (int r = 0; r < 4; ++r)
                                rec_out[((size_t)(rbase + lh * 4 + r) * T_ + (T_ - 1 - t)) * DD_ + d] = ao[r];
                        }
                    }
                }

                if (s <= T_) {
                    // h1(s-1) from ring0 slot (s-1)&1 == (s+1)&1
                    f16x8 xA0, xA1;
                    ring_read(ring0, (s + 1) & 1, l15, lh, xA0, xA1);
                    f32x4 acc[4];
#pragma unroll
                    for (int q = 0; q < 4; ++q) {
                        f32x4 a = MFMA16(xA0, xlds1[w][q * 2 + 0][lane], bias4[q]);
                        a = MFMA16(xA1, xlds1[w][q * 2 + 1][lane], a);
                        a = MFMA16(hA0, wlds1[w][q * 2 + 0][lane], a);
                        a = MFMA16(hA1, wlds1[w][q * 2 + 1][lane], a);
                        acc[q] = a;
                    }
                    f16 hh[4];
                    float hvf[4];
#pragma unroll
                    for (int r = 0; r < 4; ++r) {
                        const float iv = sigmoid_(acc[0][r]);
                        const float fv = sigmoid_(acc[1][r]);
                        const float gv = tanh_(acc[2][r]);
                        const float ov = sigmoid_(acc[3][r]);
                        const float cn = fv * c4[r] + iv * gv;
                        c4[r] = cn;
                        hvf[r] = ov * tanh_(cn);
                        hh[r] = (f16)hvf[r];
                    }
                    // write h2(s-1) to ring1 slot (s-1)&1 == (s+1)&1
                    ring_write(ring1, (s + 1) & 1, w, l15, lh, hh);
                    if (!IS_DEC && s == T_) {
#pragma unroll
                        for (int r = 0; r < 4; ++r)
                            hT_out[(size_t)(rbase + lh * 4 + r) * H_ + w * 16 + l15] = hvf[r];
                    }
                }
            }
        }
        __syncthreads();
    }
}

// latent = hT2 @ tlW^T + tlb ; h0 = latent @ flW^T + flb   (tiny, fp32 VALU)
__global__ __launch_bounds__(256)
void latent_k(const float* __restrict__ hT, const float* __restrict__ tlW,
              const float* __restrict__ tlb, const float* __restrict__ flW,
              const float* __restrict__ flb, float* __restrict__ lat_out,
              float* __restrict__ h0_out)
{
    __shared__ float lat[64][L_];
    const int tid = threadIdx.x;
    const int r = tid >> 2;
    const int rb = blockIdx.x * 64;

    float hr[H_];
    const float* hrow = hT + (size_t)(rb + r) * H_;
#pragma unroll
    for (int k = 0; k < H_; ++k) hr[k] = hrow[k];

    const int c8 = (tid & 3) * 8;
#pragma unroll
    for (int jj = 0; jj < 8; ++jj) {
        const int l = c8 + jj;
        float s = tlb[l];
        const float* wrow = tlW + l * H_;
#pragma unroll
        for (int k = 0; k < H_; ++k) s += hr[k] * wrow[k];
        lat[r][l] = s;
        lat_out[(size_t)(rb + r) * L_ + l] = s;
    }
    __syncthreads();

    float lr[L_];
#pragma unroll
    for (int k = 0; k < L_; ++k) lr[k] = lat[r][k];
    const int hc16 = (tid & 3) * 16;
#pragma unroll
    for (int jj = 0; jj < 16; ++jj) {
        const int hc = hc16 + jj;
        float s = flb[hc];
        const float* wrow = flW + hc * L_;
#pragma unroll
        for (int k = 0; k < L_; ++k) s += lr[k] * wrow[k];
        h0_out[(size_t)(rb + r) * H_ + hc] = s;
    }
}

extern "C" void kernel_launch(void* const* d_in, const int* in_sizes, int n_in,
                              void* d_out, int out_size, void* d_ws, size_t ws_size,
                              hipStream_t stream)
{
    const float* x     = (const float*)d_in[0];
    const float* eWih0 = (const float*)d_in[1];
    const float* eWhh0 = (const float*)d_in[2];
    const float* ebih0 = (const float*)d_in[3];
    const float* ebhh0 = (const float*)d_in[4];
    const float* eWih1 = (const float*)d_in[5];
    const float* eWhh1 = (const float*)d_in[6];
    const float* ebih1 = (const float*)d_in[7];
    const float* ebhh1 = (const float*)d_in[8];
    const float* dWih0 = (const float*)d_in[9];
    const float* dWhh0 = (const float*)d_in[10];
    const float* dbih0 = (const float*)d_in[11];
    const float* dbhh0 = (const float*)d_in[12];
    const float* dWih1 = (const float*)d_in[13];
    const float* dWhh1 = (const float*)d_in[14];
    const float* dbih1 = (const float*)d_in[15];
    const float* dbhh1 = (const float*)d_in[16];
    const float* tlW   = (const float*)d_in[17];
    const float* tlb   = (const float*)d_in[18];
    const float* flW   = (const float*)d_in[19];
    const float* flb   = (const float*)d_in[20];
    const float* outW  = (const float*)d_in[21];
    const float* outb  = (const float*)d_in[22];

    float* rec = (float*)d_out;                       // [B,T,21] fp32
    float* lat = rec + (size_t)B_ * T_ * DD_;         // [B,32]  fp32

    char* ws = (char*)d_ws;
    f16*   xpad = (f16*)ws;                                            // [B,T,32] f16
    float* hT2  = (float*)(ws + (size_t)B_ * T_ * DP_ * 2);            // [B,64]
    float* h0   = (float*)(ws + (size_t)B_ * T_ * DP_ * 2 + (size_t)B_ * H_ * 4); // [B,64]

    // pad/cast x once per call
    padx_k<<<dim3(B_ * T_ * 8 / 256), dim3(256), 0, stream>>>(x, xpad);
    // fused encoder pair -> hT2
    lstm_pair_k<false><<<dim3(B_ / 16), dim3(512), 0, stream>>>(
        xpad, eWih0, eWhh0, ebih0, ebhh0, eWih1, eWhh1, ebih1, ebhh1,
        nullptr, hT2, nullptr, nullptr, nullptr);
    // latent + decoder initial h
    latent_k<<<dim3(B_ / 64), dim3(256), 0, stream>>>(hT2, tlW, tlb, flW, flb, lat, h0);
    // fused decoder pair -> rec (fused out-proj, time-reversed store)
    lstm_pair_k<true><<<dim3(B_ / 16), dim3(512), 0, stream>>>(
        xpad, dWih0, dWhh0, dbih0, dbhh0, dWih1, dWhh1, dbih1, dbhh1,
        h0, nullptr, outW, outb, rec);
}

// Round 4
// 394.457 us; speedup vs baseline: 1.7695x; 1.0563x over previous
//
#include <hip/hip_runtime.h>

#define B_ 4096
#define T_ 128
#define DD_ 21
#define H_ 64
#define L_ 32
#define DP_ 32   // layer-0 input dim padded to 32 (f16)

typedef _Float16 f16;
typedef _Float16 f16x8 __attribute__((ext_vector_type(8)));
typedef _Float16 f16x4 __attribute__((ext_vector_type(4)));
typedef float f32x4 __attribute__((ext_vector_type(4)));

#if __has_builtin(__builtin_amdgcn_exp2f)
#define EXP2F(x) __builtin_amdgcn_exp2f(x)
#else
#define EXP2F(x) exp2f(x)
#endif
#if __has_builtin(__builtin_amdgcn_rcpf)
#define RCPF(x) __builtin_amdgcn_rcpf(x)
#else
#define RCPF(x) (1.0f / (x))
#endif

__device__ __forceinline__ float sigmoid_(float x) {
    return RCPF(1.0f + EXP2F(-1.4426950408889634f * x));
}
__device__ __forceinline__ float tanh_(float x) {
    return 1.0f - 2.0f * RCPF(1.0f + EXP2F(2.8853900817779268f * x));
}

#define MFMA16(A, Bf, C) __builtin_amdgcn_mfma_f32_16x16x32_f16((A), (Bf), (C), 0, 0, 0)

// ---- h ring helpers: [slots][16 rows][64 cols] f16, XOR-swizzled rows ----
// write side: D-frag (row=lh*4+r, col=w*16+l15); read side: A-frag (row=l15, k)
__device__ __forceinline__ void ring_read(const f16* ring, int slot, int l15, int lh,
                                          f16x8& a0, f16x8& a1) {
    const char* base = (const char*)(ring + slot * 1024);
    const int sw = (l15 & 7) << 4;
    a0 = *(const f16x8*)(base + l15 * 128 + ((lh * 16) ^ sw));
    a1 = *(const f16x8*)(base + l15 * 128 + ((64 + lh * 16) ^ sw));
}
__device__ __forceinline__ void ring_write(f16* ring, int slot, int w, int l15, int lh,
                                           const f16* hh) {
    char* base = (char*)(ring + slot * 1024);
    const int colb = (w * 16 + l15) * 2;
#pragma unroll
    for (int r = 0; r < 4; ++r) {
        const int row = lh * 4 + r;
        *(f16*)(base + row * 128 + (colb ^ ((row & 7) << 4))) = hh[r];
    }
}

// x pad/cast: x f32 [B,T,21] -> xpad f16 [B,T,32] (zero-padded)
__global__ __launch_bounds__(256)
void padx_k(const float* __restrict__ x, f16* __restrict__ xpad)
{
    const int idx = blockIdx.x * blockDim.x + threadIdx.x;   // B*T*8 groups of 4
    const size_t bt = (size_t)(idx >> 3);
    const int k0 = (idx & 7) * 4;
    const float* src = x + bt * DD_;
    f16x4 v;
#pragma unroll
    for (int j = 0; j < 4; ++j) {
        const int k = k0 + j;
        v[j] = (k < DD_) ? (f16)src[k] : (f16)0.0f;
    }
    *(f16x4*)(xpad + bt * DP_ + k0) = v;
}

// Fused layer pair with 1-step pipeline skew, weights in VGPRs.
// Block: 512 threads = 8 waves. Waves 0-3: layer0 (t=s), waves 4-7: layer1 (t=s-1).
// h1 flows layer0->layer1 through ring0; ring1 is layer1's own recurrence.
// All weight fragments live in registers (loaded once, statically indexed);
// LDS holds only the two 2-slot h rings (8 KB). amdgpu_waves_per_eu(2,2) tells
// the allocator occupancy >2 waves/EU is pointless => may use up to 256 VGPRs.
// IS_DEC: layer0 reads x reversed, both layers start from h0p; output projection
// runs on grp0 waves 2-3 (rebalances MFMA: grp1 16/step, grp0 12+2/step).
template<bool IS_DEC>
__global__
__attribute__((amdgpu_flat_work_group_size(512, 512), amdgpu_waves_per_eu(2, 2)))
void lstm_pair_k(const f16* __restrict__ xpad,
                 const float* __restrict__ Wih0, const float* __restrict__ Whh0,
                 const float* __restrict__ bih0, const float* __restrict__ bhh0,
                 const float* __restrict__ Wih1, const float* __restrict__ Whh1,
                 const float* __restrict__ bih1, const float* __restrict__ bhh1,
                 const float* __restrict__ h0p,
                 float* __restrict__ hT_out,
                 const float* __restrict__ outW, const float* __restrict__ outb,
                 float* __restrict__ rec_out)
{
    __shared__ __align__(16) f16 ring0[2 * 1024];   // h1 ring (4 KB)
    __shared__ __align__(16) f16 ring1[2 * 1024];   // h2 ring (4 KB)

    const int tid  = threadIdx.x;
    const int wv   = tid >> 6;
    const int grp  = wv >> 2;         // 0: layer0, 1: layer1
    const int w    = wv & 3;
    const int lane = tid & 63;
    const int l15  = lane & 15;
    const int lh   = lane >> 4;
    const int rbase = blockIdx.x * 16;

    const float* Wih = grp ? Wih1 : Wih0;
    const float* Whh = grp ? Whh1 : Whh0;
    const float* bih = grp ? bih1 : bih0;
    const float* bhh = grp ? bhh1 : bhh0;

    // ---- weight fragments -> VGPRs (B-frag: col = l15, k = lh*8 + j) ----
    f16x8 wR[8];    // Whh frags [q*2+kt]
    f16x8 xR[8];    // Wih frags: grp1 [q*2+kt]; grp0 [q] (K=32)
    f32x4 bias4[4];
#pragma unroll
    for (int q = 0; q < 4; ++q) {
        const int g = (w + 4 * q) * 16 + l15;   // gate row in W; q=0:i 1:f 2:g 3:o
#pragma unroll
        for (int kt = 0; kt < 2; ++kt) {
            const float* p = Whh + g * H_ + kt * 32 + lh * 8;
            f16x8 v;
#pragma unroll
            for (int j = 0; j < 8; ++j) v[j] = (f16)p[j];
            wR[q * 2 + kt] = v;
        }
        if (grp) {
#pragma unroll
            for (int kt = 0; kt < 2; ++kt) {
                const float* p = Wih + g * H_ + kt * 32 + lh * 8;
                f16x8 v;
#pragma unroll
                for (int j = 0; j < 8; ++j) v[j] = (f16)p[j];
                xR[q * 2 + kt] = v;
            }
        } else {
            const float* p = Wih + g * DD_;     // real row length 21
            f16x8 v;
#pragma unroll
            for (int j = 0; j < 8; ++j) {
                const int k = lh * 8 + j;
                v[j] = (k < DD_) ? (f16)p[k] : (f16)0.0f;
            }
            xR[q] = v;
        }
        const float bv = bih[g] + bhh[g];
        bias4[q] = (f32x4){bv, bv, bv, bv};
    }

    // out-projection frags: dec only, grp0 waves 2-3 (d = (w-2)*16 + l15)
    f16x8 bO[2];
    float obias = 0.0f;
    if (IS_DEC && grp == 0) {
        const bool pvalid = (w >= 2) && ((w - 2) * 16 + l15 < DD_);
        const int d = pvalid ? ((w - 2) * 16 + l15) : 0;
#pragma unroll
        for (int kt = 0; kt < 2; ++kt) {
            f16x8 v;
#pragma unroll
            for (int j = 0; j < 8; ++j)
                v[j] = pvalid ? (f16)outW[d * H_ + kt * 32 + lh * 8 + j] : (f16)0.0f;
            bO[kt] = v;
        }
        if (pvalid) obias = outb[d];
    }

    // ---- init ring slot 1 with h(-1): h0p (dec) or zeros (enc) ----
    {
        f16* ring = (tid < 256) ? ring0 : ring1;
        const int i = tid & 255;
        const int row = i >> 4;
        const int cq = i & 15;
        f16x4 v;
#pragma unroll
        for (int j = 0; j < 4; ++j)
            v[j] = IS_DEC ? (f16)h0p[(size_t)(rbase + row) * H_ + cq * 4 + j] : (f16)0.0f;
        char* base = (char*)(ring + 1024);
        *(f16x4*)(base + row * 128 + ((cq * 8) ^ ((row & 7) << 4))) = v;
    }

    f32x4 c4 = {0.f, 0.f, 0.f, 0.f};

    // ---- layer0 x prefetch ring (distance 2) ----
    auto xaddr = [&](int t) -> const f16* {
        const int trd = IS_DEC ? (T_ - 1 - t) : t;
        return xpad + ((size_t)(rbase + l15) * T_ + trd) * DP_ + lh * 8;
    };
    f16x8 xA, pf[2];
    if (grp == 0) {
        xA = *(const f16x8*)xaddr(0);
        pf[1] = *(const f16x8*)xaddr(1);
    }

    __syncthreads();   // ring init visible

    // ---- pipelined main loop; 130 block-steps ----
#pragma unroll 2
    for (int s = 0; s < 130; ++s) {
        if (grp == 0) {
            if (s < T_) {
                // prefetch x(s+2)
                const int tf = (s + 2 < T_) ? s + 2 : T_ - 1;
                pf[s & 1] = *(const f16x8*)xaddr(tf);
                // h1(s-1) from ring0 slot (s-1)&1 == (s+1)&1
                f16x8 hA0, hA1;
                ring_read(ring0, (s + 1) & 1, l15, lh, hA0, hA1);
                f32x4 acc[4];
#pragma unroll
                for (int q = 0; q < 4; ++q) {
                    f32x4 a = MFMA16(xA, xR[q], bias4[q]);
                    a = MFMA16(hA0, wR[q * 2 + 0], a);
                    a = MFMA16(hA1, wR[q * 2 + 1], a);
                    acc[q] = a;
                }
                f16 hh[4];
#pragma unroll
                for (int r = 0; r < 4; ++r) {
                    const float iv = sigmoid_(acc[0][r]);
                    const float fv = sigmoid_(acc[1][r]);
                    const float gv = tanh_(acc[2][r]);
                    const float ov = sigmoid_(acc[3][r]);
                    const float cn = fv * c4[r] + iv * gv;
                    c4[r] = cn;
                    hh[r] = (f16)(ov * tanh_(cn));
                }
                ring_write(ring0, s & 1, w, l15, lh, hh);
                xA = pf[(s + 1) & 1];
            }
            // deferred output projection of h2(s-2) on waves 2-3 (dec only)
            if (IS_DEC && s >= 2 && w >= 2) {
                f16x8 pA0, pA1;
                ring_read(ring1, s & 1, l15, lh, pA0, pA1);
                f32x4 ao = {obias, obias, obias, obias};
                ao = MFMA16(pA0, bO[0], ao);
                ao = MFMA16(pA1, bO[1], ao);
                const int d = (w - 2) * 16 + l15;
                if (d < DD_) {
                    const int t = s - 2;
#pragma unroll
                    for (int r = 0; r < 4; ++r)
                        rec_out[((size_t)(rbase + lh * 4 + r) * T_ + (T_ - 1 - t)) * DD_ + d] = ao[r];
                }
            }
        } else {
            if (s >= 1 && s <= T_) {
                // own recurrence h2(s-2) from ring1 slot (s-2)&1 == s&1
                f16x8 hA0, hA1;
                ring_read(ring1, s & 1, l15, lh, hA0, hA1);
                // h1(s-1) from ring0 slot (s-1)&1 == (s+1)&1
                f16x8 xA0, xA1;
                ring_read(ring0, (s + 1) & 1, l15, lh, xA0, xA1);
                f32x4 acc[4];
#pragma unroll
                for (int q = 0; q < 4; ++q) {
                    f32x4 a = MFMA16(xA0, xR[q * 2 + 0], bias4[q]);
                    a = MFMA16(xA1, xR[q * 2 + 1], a);
                    a = MFMA16(hA0, wR[q * 2 + 0], a);
                    a = MFMA16(hA1, wR[q * 2 + 1], a);
                    acc[q] = a;
                }
                f16 hh[4];
                float hvf[4];
#pragma unroll
                for (int r = 0; r < 4; ++r) {
                    const float iv = sigmoid_(acc[0][r]);
                    const float fv = sigmoid_(acc[1][r]);
                    const float gv = tanh_(acc[2][r]);
                    const float ov = sigmoid_(acc[3][r]);
                    const float cn = fv * c4[r] + iv * gv;
                    c4[r] = cn;
                    hvf[r] = ov * tanh_(cn);
                    hh[r] = (f16)hvf[r];
                }
                // write h2(s-1) to ring1 slot (s-1)&1 == (s+1)&1
                ring_write(ring1, (s + 1) & 1, w, l15, lh, hh);
                if (!IS_DEC && s == T_) {
#pragma unroll
                    for (int r = 0; r < 4; ++r)
                        hT_out[(size_t)(rbase + lh * 4 + r) * H_ + w * 16 + l15] = hvf[r];
                }
            }
        }
        __syncthreads();
    }
}

// latent = hT2 @ tlW^T + tlb ; h0 = latent @ flW^T + flb   (tiny, fp32 VALU)
__global__ __launch_bounds__(256)
void latent_k(const float* __restrict__ hT, const float* __restrict__ tlW,
              const float* __restrict__ tlb, const float* __restrict__ flW,
              const float* __restrict__ flb, float* __restrict__ lat_out,
              float* __restrict__ h0_out)
{
    __shared__ float lat[64][L_];
    const int tid = threadIdx.x;
    const int r = tid >> 2;
    const int rb = blockIdx.x * 64;

    float hr[H_];
    const float* hrow = hT + (size_t)(rb + r) * H_;
#pragma unroll
    for (int k = 0; k < H_; ++k) hr[k] = hrow[k];

    const int c8 = (tid & 3) * 8;
#pragma unroll
    for (int jj = 0; jj < 8; ++jj) {
        const int l = c8 + jj;
        float s = tlb[l];
        const float* wrow = tlW + l * H_;
#pragma unroll
        for (int k = 0; k < H_; ++k) s += hr[k] * wrow[k];
        lat[r][l] = s;
        lat_out[(size_t)(rb + r) * L_ + l] = s;
    }
    __syncthreads();

    float lr[L_];
#pragma unroll
    for (int k = 0; k < L_; ++k) lr[k] = lat[r][k];
    const int hc16 = (tid & 3) * 16;
#pragma unroll
    for (int jj = 0; jj < 16; ++jj) {
        const int hc = hc16 + jj;
        float s = flb[hc];
        const float* wrow = flW + hc * L_;
#pragma unroll
        for (int k = 0; k < L_; ++k) s += lr[k] * wrow[k];
        h0_out[(size_t)(rb + r) * H_ + hc] = s;
    }
}

extern "C" void kernel_launch(void* const* d_in, const int* in_sizes, int n_in,
                              void* d_out, int out_size, void* d_ws, size_t ws_size,
                              hipStream_t stream)
{
    const float* x     = (const float*)d_in[0];
    const float* eWih0 = (const float*)d_in[1];
    const float* eWhh0 = (const float*)d_in[2];
    const float* ebih0 = (const float*)d_in[3];
    const float* ebhh0 = (const float*)d_in[4];
    const float* eWih1 = (const float*)d_in[5];
    const float* eWhh1 = (const float*)d_in[6];
    const float* ebih1 = (const float*)d_in[7];
    const float* ebhh1 = (const float*)d_in[8];
    const float* dWih0 = (const float*)d_in[9];
    const float* dWhh0 = (const float*)d_in[10];
    const float* dbih0 = (const float*)d_in[11];
    const float* dbhh0 = (const float*)d_in[12];
    const float* dWih1 = (const float*)d_in[13];
    const float* dWhh1 = (const float*)d_in[14];
    const float* dbih1 = (const float*)d_in[15];
    const float* dbhh1 = (const float*)d_in[16];
    const float* tlW   = (const float*)d_in[17];
    const float* tlb   = (const float*)d_in[18];
    const float* flW   = (const float*)d_in[19];
    const float* flb   = (const float*)d_in[20];
    const float* outW  = (const float*)d_in[21];
    const float* outb  = (const float*)d_in[22];

    float* rec = (float*)d_out;                       // [B,T,21] fp32
    float* lat = rec + (size_t)B_ * T_ * DD_;         // [B,32]  fp32

    char* ws = (char*)d_ws;
    f16*   xpad = (f16*)ws;                                            // [B,T,32] f16
    float* hT2  = (float*)(ws + (size_t)B_ * T_ * DP_ * 2);            // [B,64]
    float* h0   = (float*)(ws + (size_t)B_ * T_ * DP_ * 2 + (size_t)B_ * H_ * 4); // [B,64]

    // pad/cast x once per call
    padx_k<<<dim3(B_ * T_ * 8 / 256), dim3(256), 0, stream>>>(x, xpad);
    // fused encoder pair -> hT2
    lstm_pair_k<false><<<dim3(B_ / 16), dim3(512), 0, stream>>>(
        xpad, eWih0, eWhh0, ebih0, ebhh0, eWih1, eWhh1, ebih1, ebhh1,
        nullptr, hT2, nullptr, nullptr, nullptr);
    // latent + decoder initial h
    latent_k<<<dim3(B_ / 64), dim3(256), 0, stream>>>(hT2, tlW, tlb, flW, flb, lat, h0);
    // fused decoder pair -> rec (fused out-proj on grp0 w2-3, time-reversed store)
    lstm_pair_k<true><<<dim3(B_ / 16), dim3(512), 0, stream>>>(
        xpad, dWih0, dWhh0, dbih0, dbhh0, dWih1, dWhh1, dbih1, dbhh1,
        h0, nullptr, outW, outb, rec);
}